// Round 5
// baseline (1193.677 us; speedup 1.0000x reference)
//
#include <hip/hip_runtime.h>

typedef unsigned short u16;
typedef unsigned int   u32;
typedef __attribute__((ext_vector_type(8))) short s16x8;   // 8 x bf16 MFMA frag
typedef __attribute__((ext_vector_type(4))) float f32x4;

__device__ __forceinline__ u16 f2bf(float f) {
  u32 u = __builtin_bit_cast(u32, f);
  return (u16)((u + 0x7FFFu + ((u >> 16) & 1u)) >> 16);   // RNE
}
__device__ __forceinline__ float bf2f(u16 h) {
  return __builtin_bit_cast(float, (u32)h << 16);
}
__device__ __forceinline__ u32 pack2(float a, float b) {
  return (u32)f2bf(a) | ((u32)f2bf(b) << 16);
}

// ---------------- K0: weight f32 -> bf16 ----------------
__global__ __launch_bounds__(256) void k_wcvt(const float* __restrict__ wq,
                                              const float* __restrict__ wp,
                                              u16* __restrict__ wq_bf,
                                              u16* __restrict__ wp_bf) {
  int i = blockIdx.x * 256 + threadIdx.x;
  if (i < 576 * 192) wq_bf[i] = f2bf(wq[i]);
  if (i < 192 * 192) wp_bf[i] = f2bf(wp[i]);
}

// ---------------- K_shuf: x (NCHW f32) -> xs (shuffled NHWC bf16 [p'][192]) --
__global__ __launch_bounds__(512) void k_shuf(const float* __restrict__ x,
                                              u16* __restrict__ xs) {
  __shared__ __align__(16) u16 Xs[256 * 104];   // [n=256][c=96 pad 104] = 53KB
  const int t  = threadIdx.x;
  const int b  = blockIdx.y;
  const int h1 = blockIdx.x >> 1;
  const int cg = blockIdx.x & 1;                 // channels [cg*96, cg*96+96)
  const float* xb = x + (size_t)b * 12582912 + (size_t)cg * 96 * 65536;
  const int hbase = h1 >> 2;
  const int wbase = (h1 & 3) << 4;
#pragma unroll
  for (int it = 0; it < 6; ++it) {
    const int idx = it * 512 + t;          // 3072 units
    const int f = idx & 3;                 // float4 within 64B run
    const int r = (idx >> 2) & 15;         // run id
    const int c = (idx >> 6) * 2;          // local even channel 0..94
    const int ho = ((r >> 2) & 3) * 64 + hbase;
    const int wo = (r & 3) * 64 + wbase + f * 4;
    const float* s0 = xb + (size_t)c * 65536 + (size_t)ho * 256 + wo;
    float4 v0 = *(const float4*)s0;
    float4 v1 = *(const float4*)(s0 + 65536);
    const int nb = 64 * f + r;             // n = nb + 16q
    *(u32*)&Xs[(nb     ) * 104 + c] = pack2(v0.x, v1.x);
    *(u32*)&Xs[(nb + 16) * 104 + c] = pack2(v0.y, v1.y);
    *(u32*)&Xs[(nb + 32) * 104 + c] = pack2(v0.z, v1.z);
    *(u32*)&Xs[(nb + 48) * 104 + c] = pack2(v0.w, v1.w);
  }
  __syncthreads();
  // linear write-out: this block's half-row region = 256 px * 192B
  char* const xsb = (char*)xs + (size_t)b * 100663296 + (size_t)h1 * 98304 + cg * 192;
#pragma unroll
  for (int it = 0; it < 6; ++it) {
    const int off = it * 8192 + t * 16;    // byte offset in compacted half
    const int px = off / 192;
    const int cb = off - px * 192;         // 0..176
    uint4 v = *(const uint4*)((const char*)Xs + px * 208 + cb);
    *(uint4*)(xsb + (size_t)px * 384 + cb) = v;
  }
}

// ---------------- K1: qkv 1x1 conv (GEMM M=576,K=192) -> NHWC --------------
// Zero LDS, zero barriers. bv hoisted from xs (16B/lane, 64B segs), af from
// L2-resident wq, acc stored directly to qkvn[px][576] (16 px x 32B segs per
// instr; sibling instrs fill full 128B regions -> L2 write-merge).
__global__ __launch_bounds__(256, 4) void k_qkv(const u16* __restrict__ xs,
                                                const u16* __restrict__ wq,
                                                u16* __restrict__ qkvn) {
  const int t = threadIdx.x;
  const int b = blockIdx.y;
  const int lane = t & 63, wid = t >> 6;         // 4 waves, 32 px each
  const int lm = lane & 15, lk = lane >> 4;
  const int px0 = blockIdx.x * 128 + wid * 32 + lm;
  const u16* xrow0 = xs + (size_t)b * 50331648 + (size_t)px0 * 192;
  s16x8 bv[2][6];
#pragma unroll
  for (int nf = 0; nf < 2; ++nf) {
#pragma unroll
    for (int kk = 0; kk < 6; ++kk)
      bv[nf][kk] = *(const s16x8*)(xrow0 + (size_t)nf * 16 * 192 + kk * 32 + lk * 8);
  }
  u16* const ob = qkvn + (size_t)b * 37748736 + (size_t)px0 * 576;

#pragma unroll 1
  for (int mt = 0; mt < 9; ++mt) {
    f32x4 acc[4][2];
#pragma unroll
    for (int i = 0; i < 4; ++i) {
      acc[i][0] = f32x4{0.f, 0.f, 0.f, 0.f};
      acc[i][1] = f32x4{0.f, 0.f, 0.f, 0.f};
    }
#pragma unroll
    for (int kk = 0; kk < 6; ++kk) {
      s16x8 af[4];
#pragma unroll
      for (int mf = 0; mf < 4; ++mf)
        af[mf] = *(const s16x8*)&wq[(size_t)(mt * 64 + mf * 16 + lm) * 192 + kk * 32 + lk * 8];
#pragma unroll
      for (int mf = 0; mf < 4; ++mf) {
#pragma unroll
        for (int nf = 0; nf < 2; ++nf)
          acc[mf][nf] = __builtin_amdgcn_mfma_f32_16x16x32_bf16(af[mf], bv[nf][kk], acc[mf][nf], 0, 0, 0);
      }
    }
    // direct NHWC store: thread owns 4 contiguous m at px0(+16nf)
#pragma unroll
    for (int mf = 0; mf < 4; ++mf) {
#pragma unroll
      for (int nf = 0; nf < 2; ++nf) {
        const int m0 = mt * 64 + mf * 16 + lk * 4;
        uint2 o;
        o.x = pack2(acc[mf][nf][0], acc[mf][nf][1]);
        o.y = pack2(acc[mf][nf][2], acc[mf][nf][3]);
        *(uint2*)(ob + (size_t)nf * 16 * 576 + m0) = o;
      }
    }
  }
}

// ---------------- K2: depthwise 3x3, pad 1, NHWC bf16 -> NCHW bf16 --------
// Lanes channel-fast (64ch = 128B seg per load instr); thread = 1ch x 8px;
// single uint4 NCHW store per thread (4 pxoct waves fill each 64B sector).
__global__ __launch_bounds__(256) void k_dw(const u16* __restrict__ qkvn,
                                            const float* __restrict__ wdw,
                                            u16* __restrict__ qkvb) {
  const int t = threadIdx.x;
  const int bx = blockIdx.x;                 // (h<<3)|strip
  const int cg = blockIdx.y;                 // 9 groups of 64 ch
  const int b  = blockIdx.z;
  const int c  = cg * 64 + (t & 63);
  const int pxoct = t >> 6;
  const int h  = bx >> 3;
  const int w0 = (bx & 7) * 32 + pxoct * 8;
  float w9[9];
#pragma unroll
  for (int i = 0; i < 9; ++i) w9[i] = wdw[c * 9 + i];
  const u16* inb = qkvn + (size_t)b * 37748736 + c;
  float acc[8] = {0.f,0.f,0.f,0.f,0.f,0.f,0.f,0.f};
#pragma unroll
  for (int ky = 0; ky < 3; ++ky) {
    const int hh = h + ky - 1;
    if (hh < 0 || hh > 255) continue;
    const u16* rowp = inb + (size_t)hh * 147456;   // 256 px * 576
    float e[10];
#pragma unroll
    for (int wx = 0; wx < 10; ++wx) {
      const int ww = w0 - 1 + wx;
      e[wx] = (ww >= 0 && ww <= 255) ? bf2f(rowp[(size_t)ww * 576]) : 0.f;
    }
#pragma unroll
    for (int kx = 0; kx < 3; ++kx) {
      const float wk = w9[ky * 3 + kx];
#pragma unroll
      for (int j = 0; j < 8; ++j) acc[j] += wk * e[j + kx];
    }
  }
  u32 o[4];
#pragma unroll
  for (int q = 0; q < 4; ++q)
    o[q] = pack2(acc[2 * q], acc[2 * q + 1]);
  *(uint4*)(qkvb + ((size_t)b * 576 + c) * 65536 + h * 256 + w0) = make_uint4(o[0], o[1], o[2], o[3]);
}

// ---------------- K3: raw-reshape windowed MSA ----------------------------
__global__ __launch_bounds__(256) void k_msa(const u16* __restrict__ qkvb,
                                             u16* __restrict__ attnb) {
  const int t = threadIdx.x;
  const int b = blockIdx.y;
  const int g = blockIdx.x * 32 + (t >> 3);
  const int head = t & 7;
  const int gh = g >> 7, gw = g & 127;
  const u16* qb = qkvb + (size_t)b * 37748736;
  u16* ab = attnb + (size_t)b * 12582912;
  int poff[4];
#pragma unroll
  for (int tt = 0; tt < 4; ++tt)
    poff[tt] = (2 * gh + (tt >> 1)) * 256 + 2 * gw + (tt & 1);
  uint4 kreg[4][3], vreg[4][3];
#pragma unroll
  for (int tt = 0; tt < 4; ++tt) {
    const u16* sp = qb + (size_t)poff[tt] * 576 + head * 24;
#pragma unroll
    for (int cc = 0; cc < 3; ++cc) {
      kreg[tt][cc] = *(const uint4*)(sp + 192 + cc * 8);
      vreg[tt][cc] = *(const uint4*)(sp + 384 + cc * 8);
    }
  }
#pragma unroll
  for (int tq = 0; tq < 4; ++tq) {
    const u16* sp = qb + (size_t)poff[tq] * 576 + head * 24;
    float qf[24];
#pragma unroll
    for (int cc = 0; cc < 3; ++cc) {
      uint4 v = *(const uint4*)(sp + cc * 8);
      u32 uu[4] = {v.x, v.y, v.z, v.w};
#pragma unroll
      for (int q = 0; q < 4; ++q) {
        qf[cc * 8 + 2 * q]     = bf2f((u16)(uu[q] & 0xffffu));
        qf[cc * 8 + 2 * q + 1] = bf2f((u16)(uu[q] >> 16));
      }
    }
    float s[4];
#pragma unroll
    for (int tk = 0; tk < 4; ++tk) {
      float d = 0.f;
#pragma unroll
      for (int cc = 0; cc < 3; ++cc) {
        uint4 v = kreg[tk][cc];
        u32 uu[4] = {v.x, v.y, v.z, v.w};
#pragma unroll
        for (int q = 0; q < 4; ++q) {
          d += qf[cc * 8 + 2 * q]     * bf2f((u16)(uu[q] & 0xffffu));
          d += qf[cc * 8 + 2 * q + 1] * bf2f((u16)(uu[q] >> 16));
        }
      }
      s[tk] = d * 0.35355339059327373f;   // SCALE = HEADS^-0.5
    }
    float mx = fmaxf(fmaxf(s[0], s[1]), fmaxf(s[2], s[3]));
    float e0 = __expf(s[0] - mx), e1 = __expf(s[1] - mx);
    float e2 = __expf(s[2] - mx), e3 = __expf(s[3] - mx);
    float inv = 1.f / (e0 + e1 + e2 + e3);
    float aw[4] = {e0 * inv, e1 * inv, e2 * inv, e3 * inv};
    float of[24];
#pragma unroll
    for (int dd = 0; dd < 24; ++dd) of[dd] = 0.f;
#pragma unroll
    for (int tk = 0; tk < 4; ++tk) {
#pragma unroll
      for (int cc = 0; cc < 3; ++cc) {
        uint4 v = vreg[tk][cc];
        u32 uu[4] = {v.x, v.y, v.z, v.w};
#pragma unroll
        for (int q = 0; q < 4; ++q) {
          of[cc * 8 + 2 * q]     += aw[tk] * bf2f((u16)(uu[q] & 0xffffu));
          of[cc * 8 + 2 * q + 1] += aw[tk] * bf2f((u16)(uu[q] >> 16));
        }
      }
    }
    u16* dst = ab + (size_t)poff[tq] * 192 + head * 24;
#pragma unroll
    for (int cc = 0; cc < 3; ++cc) {
      u32 o0 = pack2(of[cc * 8 + 0], of[cc * 8 + 1]);
      u32 o1 = pack2(of[cc * 8 + 2], of[cc * 8 + 3]);
      u32 o2 = pack2(of[cc * 8 + 4], of[cc * 8 + 5]);
      u32 o3 = pack2(of[cc * 8 + 6], of[cc * 8 + 7]);
      *(uint4*)(dst + cc * 8) = make_uint4(o0, o1, o2, o3);
    }
  }
}

// ---------------- K4: proj 1x1 (GEMM M=192,K=192) + shuffle_back ----------
__global__ __launch_bounds__(512) void k_proj(const u16* __restrict__ attnb,
                                              const u16* __restrict__ wp,
                                              float* __restrict__ out) {
  __shared__ __align__(16) u16 XsRaw[256 * 200];   // 102400 B; reused OutF[256][67] f32
  u16* Xs = XsRaw;
  float* OutF = (float*)XsRaw;
  const int t  = threadIdx.x;
  const int b  = blockIdx.y;
  const int hs = blockIdx.x;
  const int pix = t & 255, cg = t >> 8;
  {
    const u16* ab = attnb + (size_t)b * 12582912 + (size_t)hs * 256 + pix;
    u16* xrow = &Xs[pix * 200];
#pragma unroll 8
    for (int i = 0; i < 96; i += 2) {
      const int c = cg * 96 + i;
      u16 v0 = ab[(size_t)c * 65536];
      u16 v1 = ab[(size_t)(c + 1) * 65536];
      *(u32*)&xrow[c] = (u32)v0 | ((u32)v1 << 16);
    }
  }
  __syncthreads();
  const int lane = t & 63, wid = t >> 6;
  const int lm = lane & 15, lk = lane >> 4;
  s16x8 bv[2][6];
#pragma unroll
  for (int nf = 0; nf < 2; ++nf) {
#pragma unroll
    for (int kk = 0; kk < 6; ++kk)
      bv[nf][kk] = *(const s16x8*)&Xs[(wid * 32 + nf * 16 + lm) * 200 + kk * 32 + lk * 8];
  }
  float* const ob = out + (size_t)b * 12582912;
  const int hq_base = hs >> 2;
  const int wq_base = (hs & 3) << 4;

#pragma unroll 1
  for (int mt = 0; mt < 3; ++mt) {
    f32x4 acc[4][2];
#pragma unroll
    for (int i = 0; i < 4; ++i) {
      acc[i][0] = f32x4{0.f, 0.f, 0.f, 0.f};
      acc[i][1] = f32x4{0.f, 0.f, 0.f, 0.f};
    }
#pragma unroll
    for (int kk = 0; kk < 6; ++kk) {
      s16x8 af[4];
#pragma unroll
      for (int mf = 0; mf < 4; ++mf)
        af[mf] = *(const s16x8*)&wp[(size_t)(mt * 64 + mf * 16 + lm) * 192 + kk * 32 + lk * 8];
#pragma unroll
      for (int mf = 0; mf < 4; ++mf) {
#pragma unroll
        for (int nf = 0; nf < 2; ++nf)
          acc[mf][nf] = __builtin_amdgcn_mfma_f32_16x16x32_bf16(af[mf], bv[nf][kk], acc[mf][nf], 0, 0, 0);
      }
    }
    __syncthreads();   // prior LDS reads (bv hoist / prior epilogue) complete
#pragma unroll
    for (int mf = 0; mf < 4; ++mf) {
#pragma unroll
      for (int nf = 0; nf < 2; ++nf) {
        const int n = wid * 32 + nf * 16 + lm;
        const int m0 = mf * 16 + lk * 4;
#pragma unroll
        for (int rr = 0; rr < 4; ++rr)
          OutF[n * 67 + m0 + rr] = acc[mf][nf][rr];
      }
    }
    __syncthreads();
#pragma unroll
    for (int tt = 0; tt < 2; ++tt) {
      const int id = tt * 512 + t;
      const int r = id & 15;
      const int m = id >> 4;                         // [0,64)
      const int co = mt * 64 + m;
      const int hqr = ((r >> 2) & 3) * 64 + hq_base;
      const int wq0 = (r & 3) * 64 + wq_base;
      float* dst = ob + (size_t)co * 65536 + (size_t)hqr * 256 + wq0;
#pragma unroll
      for (int jj = 0; jj < 16; jj += 4) {
        float4 vv = make_float4(OutF[(16 * (jj + 0) + r) * 67 + m],
                                OutF[(16 * (jj + 1) + r) * 67 + m],
                                OutF[(16 * (jj + 2) + r) * 67 + m],
                                OutF[(16 * (jj + 3) + r) * 67 + m]);
        *(float4*)(dst + jj) = vv;
      }
    }
  }
}

extern "C" void kernel_launch(void* const* d_in, const int* in_sizes, int n_in,
                              void* d_out, int out_size, void* d_ws, size_t ws_size,
                              hipStream_t stream) {
  const float* x   = (const float*)d_in[0];
  const float* wq  = (const float*)d_in[1];
  const float* wdw = (const float*)d_in[2];
  const float* wpr = (const float*)d_in[3];
  float* out = (float*)d_out;
  u16* ws = (u16*)d_ws;
  // layout (u16): wq_bf | wp_bf | R1 (302MB) | R2 (302MB)
  // R1: qkvn (NHWC qkv) -> attnb ; R2: xs -> qkvb (NCHW dw out)
  u16* wq_bf = ws;
  u16* wp_bf = ws + 110592;
  u16* R1 = ws + 147456;
  u16* R2 = R1 + (size_t)150994944;
  u16* qkvn  = R1;
  u16* attnb = R1;
  u16* xs    = R2;
  u16* qkvb  = R2;

  hipLaunchKernelGGL(k_wcvt, dim3(432), dim3(256), 0, stream, wq, wpr, wq_bf, wp_bf);
  hipLaunchKernelGGL(k_shuf, dim3(512, 4), dim3(512), 0, stream, x, xs);
  hipLaunchKernelGGL(k_qkv,  dim3(512, 4), dim3(256), 0, stream, xs, wq_bf, qkvn);
  hipLaunchKernelGGL(k_dw,   dim3(2048, 9, 4), dim3(256), 0, stream, qkvn, wdw, qkvb);
  hipLaunchKernelGGL(k_msa,  dim3(512, 4), dim3(256), 0, stream, qkvb, attnb);
  hipLaunchKernelGGL(k_proj, dim3(256, 4), dim3(512), 0, stream, attnb, wp_bf, out);
}

// Round 6
// 805.487 us; speedup vs baseline: 1.4819x; 1.4819x over previous
//
#include <hip/hip_runtime.h>

typedef unsigned short u16;
typedef unsigned int   u32;
typedef __attribute__((ext_vector_type(8))) short s16x8;   // 8 x bf16 MFMA frag
typedef __attribute__((ext_vector_type(4))) float f32x4;

__device__ __forceinline__ u16 f2bf(float f) {
  u32 u = __builtin_bit_cast(u32, f);
  return (u16)((u + 0x7FFFu + ((u >> 16) & 1u)) >> 16);   // RNE
}
__device__ __forceinline__ float bf2f(u16 h) {
  return __builtin_bit_cast(float, (u32)h << 16);
}
__device__ __forceinline__ u32 pack2(float a, float b) {
  return (u32)f2bf(a) | ((u32)f2bf(b) << 16);
}

// ---------------- K0: weight f32 -> bf16 ----------------
__global__ __launch_bounds__(256) void k_wcvt(const float* __restrict__ wq,
                                              const float* __restrict__ wp,
                                              u16* __restrict__ wq_bf,
                                              u16* __restrict__ wp_bf) {
  int i = blockIdx.x * 256 + threadIdx.x;
  if (i < 576 * 192) wq_bf[i] = f2bf(wq[i]);
  if (i < 192 * 192) wp_bf[i] = f2bf(wp[i]);
}

// ---------------- K_shuf: x (NCHW f32) -> xs (shuffled NHWC bf16 [p'][192]) --
__global__ __launch_bounds__(512) void k_shuf(const float* __restrict__ x,
                                              u16* __restrict__ xs) {
  __shared__ __align__(16) u16 Xs[256 * 104];   // [n=256][c=96 pad 104] = 53KB
  const int t  = threadIdx.x;
  const int b  = blockIdx.y;
  const int h1 = blockIdx.x >> 1;
  const int cg = blockIdx.x & 1;                 // channels [cg*96, cg*96+96)
  const float* xb = x + (size_t)b * 12582912 + (size_t)cg * 96 * 65536;
  const int hbase = h1 >> 2;
  const int wbase = (h1 & 3) << 4;
#pragma unroll
  for (int it = 0; it < 6; ++it) {
    const int idx = it * 512 + t;          // 3072 units
    const int f = idx & 3;                 // float4 within 64B run
    const int r = (idx >> 2) & 15;         // run id
    const int c = (idx >> 6) * 2;          // local even channel 0..94
    const int ho = ((r >> 2) & 3) * 64 + hbase;
    const int wo = (r & 3) * 64 + wbase + f * 4;
    const float* s0 = xb + (size_t)c * 65536 + (size_t)ho * 256 + wo;
    float4 v0 = *(const float4*)s0;
    float4 v1 = *(const float4*)(s0 + 65536);
    const int nb = 64 * f + r;             // n = nb + 16q
    *(u32*)&Xs[(nb     ) * 104 + c] = pack2(v0.x, v1.x);
    *(u32*)&Xs[(nb + 16) * 104 + c] = pack2(v0.y, v1.y);
    *(u32*)&Xs[(nb + 32) * 104 + c] = pack2(v0.z, v1.z);
    *(u32*)&Xs[(nb + 48) * 104 + c] = pack2(v0.w, v1.w);
  }
  __syncthreads();
  // linear write-out: this block's half-row region = 256 px * 192B
  char* const xsb = (char*)xs + (size_t)b * 100663296 + (size_t)h1 * 98304 + cg * 192;
#pragma unroll
  for (int it = 0; it < 6; ++it) {
    const int off = it * 8192 + t * 16;    // byte offset in compacted half
    const int px = off / 192;
    const int cb = off - px * 192;         // 0..176
    uint4 v = *(const uint4*)((const char*)Xs + px * 208 + cb);
    *(uint4*)(xsb + (size_t)px * 384 + cb) = v;
  }
}

// ---------------- K1: qkv 1x1 conv (GEMM M=576,K=192) -> NCHW --------------
// SWAPPED MFMA operands: mfma(X_frag, W_frag) puts px on the reg-indexed dim
// -> each lane holds 4 consecutive px of one channel = packed uint2 NCHW
// store (16 ch-planes x 32B segments/instr; 4 waves complete 128B lines).
// Zero LDS, zero barriers. bv hoisted from xs (L3-hot), W from L2.
__global__ __launch_bounds__(256) void k_qkv(const u16* __restrict__ xs,
                                             const u16* __restrict__ wq,
                                             u16* __restrict__ qkv1) {
  const int t = threadIdx.x;
  const int b = blockIdx.y;
  const int lane = t & 63, wid = t >> 6;     // 4 waves x 32 px
  const int lm = lane & 15, lk = lane >> 4;
  const int px0 = blockIdx.x * 128 + wid * 32;
  const u16* xb = xs + (size_t)b * 50331648;
  // A-frags (px rows): frag f row lm -> px = px0 + f*16 + lm
  s16x8 av[2][6];
#pragma unroll
  for (int f = 0; f < 2; ++f) {
#pragma unroll
    for (int kk = 0; kk < 6; ++kk)
      av[f][kk] = *(const s16x8*)(xb + (size_t)(px0 + f * 16 + lm) * 192 + kk * 32 + lk * 8);
  }
  u16* const ob = qkv1 + (size_t)b * 37748736;

#pragma unroll 1
  for (int mt = 0; mt < 9; ++mt) {
    f32x4 acc[2][4];
#pragma unroll
    for (int f = 0; f < 2; ++f) {
#pragma unroll
      for (int j = 0; j < 4; ++j) acc[f][j] = f32x4{0.f, 0.f, 0.f, 0.f};
    }
#pragma unroll
    for (int kk = 0; kk < 6; ++kk) {
      s16x8 wf[4];
#pragma unroll
      for (int j = 0; j < 4; ++j)
        wf[j] = *(const s16x8*)&wq[(size_t)(mt * 64 + j * 16 + lm) * 192 + kk * 32 + lk * 8];
#pragma unroll
      for (int f = 0; f < 2; ++f) {
#pragma unroll
        for (int j = 0; j < 4; ++j)
          acc[f][j] = __builtin_amdgcn_mfma_f32_16x16x32_bf16(av[f][kk], wf[j], acc[f][j], 0, 0, 0);
      }
    }
    // D[row=px][col=ch]: lane holds px = px0+f*16+4lk+rr (rr=reg), ch = mt*64+j*16+lm
#pragma unroll
    for (int f = 0; f < 2; ++f) {
#pragma unroll
      for (int j = 0; j < 4; ++j) {
        const int ch = mt * 64 + j * 16 + lm;
        const int px = px0 + f * 16 + lk * 4;
        uint2 o;
        o.x = pack2(acc[f][j][0], acc[f][j][1]);
        o.y = pack2(acc[f][j][2], acc[f][j][3]);
        *(uint2*)(ob + (size_t)ch * 65536 + px) = o;
      }
    }
  }
}

// ---------------- K2: depthwise 3x3, pad 1, NCHW bf16 -> NCHW bf16 --------
__global__ __launch_bounds__(256) void k_dw(const u16* __restrict__ qkv1,
                                            const float* __restrict__ wdw,
                                            u16* __restrict__ qkvb) {
  const int t = threadIdx.x;
  const int c = blockIdx.y;
  const int b = blockIdx.z;
  const int s0 = (blockIdx.x * 256 + t) * 8;
  const int h0 = s0 >> 8, w0 = s0 & 255;
  const size_t cb = ((size_t)b * 576 + c) * 65536;
  const u16* in = qkv1 + cb;
  float w9[9];
#pragma unroll
  for (int i = 0; i < 9; ++i) w9[i] = wdw[c * 9 + i];
  float acc[8] = {0.f,0.f,0.f,0.f,0.f,0.f,0.f,0.f};
#pragma unroll
  for (int ky = 0; ky < 3; ++ky) {
    const int nh = h0 + ky - 1;
    if (nh < 0 || nh > 255) continue;
    const u16* row = in + (size_t)nh * 256 + w0;
    uint4 mid = *(const uint4*)row;
    float e[10];
    e[0] = (w0 > 0) ? bf2f(row[-1]) : 0.f;
    u32 uu[4] = {mid.x, mid.y, mid.z, mid.w};
#pragma unroll
    for (int q = 0; q < 4; ++q) {
      e[1 + 2 * q] = bf2f((u16)(uu[q] & 0xffffu));
      e[2 + 2 * q] = bf2f((u16)(uu[q] >> 16));
    }
    e[9] = (w0 < 248) ? bf2f(row[8]) : 0.f;
#pragma unroll
    for (int kx = 0; kx < 3; ++kx) {
      const float wk = w9[ky * 3 + kx];
#pragma unroll
      for (int j = 0; j < 8; ++j) acc[j] += wk * e[j + kx];
    }
  }
  u32 o[4];
#pragma unroll
  for (int q = 0; q < 4; ++q)
    o[q] = pack2(acc[2 * q], acc[2 * q + 1]);
  *(uint4*)(qkvb + cb + s0) = make_uint4(o[0], o[1], o[2], o[3]);
}

// ---------------- K3: raw-reshape windowed MSA ----------------------------
__global__ __launch_bounds__(256) void k_msa(const u16* __restrict__ qkvb,
                                             u16* __restrict__ attnb) {
  const int t = threadIdx.x;
  const int b = blockIdx.y;
  const int g = blockIdx.x * 32 + (t >> 3);
  const int head = t & 7;
  const int gh = g >> 7, gw = g & 127;
  const u16* qb = qkvb + (size_t)b * 37748736;
  u16* ab = attnb + (size_t)b * 12582912;
  int poff[4];
#pragma unroll
  for (int tt = 0; tt < 4; ++tt)
    poff[tt] = (2 * gh + (tt >> 1)) * 256 + 2 * gw + (tt & 1);
  uint4 kreg[4][3], vreg[4][3];
#pragma unroll
  for (int tt = 0; tt < 4; ++tt) {
    const u16* sp = qb + (size_t)poff[tt] * 576 + head * 24;
#pragma unroll
    for (int cc = 0; cc < 3; ++cc) {
      kreg[tt][cc] = *(const uint4*)(sp + 192 + cc * 8);
      vreg[tt][cc] = *(const uint4*)(sp + 384 + cc * 8);
    }
  }
#pragma unroll
  for (int tq = 0; tq < 4; ++tq) {
    const u16* sp = qb + (size_t)poff[tq] * 576 + head * 24;
    float qf[24];
#pragma unroll
    for (int cc = 0; cc < 3; ++cc) {
      uint4 v = *(const uint4*)(sp + cc * 8);
      u32 uu[4] = {v.x, v.y, v.z, v.w};
#pragma unroll
      for (int q = 0; q < 4; ++q) {
        qf[cc * 8 + 2 * q]     = bf2f((u16)(uu[q] & 0xffffu));
        qf[cc * 8 + 2 * q + 1] = bf2f((u16)(uu[q] >> 16));
      }
    }
    float s[4];
#pragma unroll
    for (int tk = 0; tk < 4; ++tk) {
      float d = 0.f;
#pragma unroll
      for (int cc = 0; cc < 3; ++cc) {
        uint4 v = kreg[tk][cc];
        u32 uu[4] = {v.x, v.y, v.z, v.w};
#pragma unroll
        for (int q = 0; q < 4; ++q) {
          d += qf[cc * 8 + 2 * q]     * bf2f((u16)(uu[q] & 0xffffu));
          d += qf[cc * 8 + 2 * q + 1] * bf2f((u16)(uu[q] >> 16));
        }
      }
      s[tk] = d * 0.35355339059327373f;   // SCALE = HEADS^-0.5
    }
    float mx = fmaxf(fmaxf(s[0], s[1]), fmaxf(s[2], s[3]));
    float e0 = __expf(s[0] - mx), e1 = __expf(s[1] - mx);
    float e2 = __expf(s[2] - mx), e3 = __expf(s[3] - mx);
    float inv = 1.f / (e0 + e1 + e2 + e3);
    float aw[4] = {e0 * inv, e1 * inv, e2 * inv, e3 * inv};
    float of[24];
#pragma unroll
    for (int dd = 0; dd < 24; ++dd) of[dd] = 0.f;
#pragma unroll
    for (int tk = 0; tk < 4; ++tk) {
#pragma unroll
      for (int cc = 0; cc < 3; ++cc) {
        uint4 v = vreg[tk][cc];
        u32 uu[4] = {v.x, v.y, v.z, v.w};
#pragma unroll
        for (int q = 0; q < 4; ++q) {
          of[cc * 8 + 2 * q]     += aw[tk] * bf2f((u16)(uu[q] & 0xffffu));
          of[cc * 8 + 2 * q + 1] += aw[tk] * bf2f((u16)(uu[q] >> 16));
        }
      }
    }
    u16* dst = ab + (size_t)poff[tq] * 192 + head * 24;
#pragma unroll
    for (int cc = 0; cc < 3; ++cc) {
      u32 o0 = pack2(of[cc * 8 + 0], of[cc * 8 + 1]);
      u32 o1 = pack2(of[cc * 8 + 2], of[cc * 8 + 3]);
      u32 o2 = pack2(of[cc * 8 + 4], of[cc * 8 + 5]);
      u32 o3 = pack2(of[cc * 8 + 6], of[cc * 8 + 7]);
      *(uint4*)(dst + cc * 8) = make_uint4(o0, o1, o2, o3);
    }
  }
}

// ---------------- K4: proj 1x1 (GEMM M=192,K=192) + shuffle_back ----------
__global__ __launch_bounds__(512) void k_proj(const u16* __restrict__ attnb,
                                              const u16* __restrict__ wp,
                                              float* __restrict__ out) {
  __shared__ __align__(16) u16 XsRaw[256 * 200];   // 102400 B; reused OutF[256][67] f32
  u16* Xs = XsRaw;
  float* OutF = (float*)XsRaw;
  const int t  = threadIdx.x;
  const int b  = blockIdx.y;
  const int hs = blockIdx.x;
  const int pix = t & 255, cg = t >> 8;
  {
    const u16* ab = attnb + (size_t)b * 12582912 + (size_t)hs * 256 + pix;
    u16* xrow = &Xs[pix * 200];
#pragma unroll 8
    for (int i = 0; i < 96; i += 2) {
      const int c = cg * 96 + i;
      u16 v0 = ab[(size_t)c * 65536];
      u16 v1 = ab[(size_t)(c + 1) * 65536];
      *(u32*)&xrow[c] = (u32)v0 | ((u32)v1 << 16);
    }
  }
  __syncthreads();
  const int lane = t & 63, wid = t >> 6;
  const int lm = lane & 15, lk = lane >> 4;
  s16x8 bv[2][6];
#pragma unroll
  for (int nf = 0; nf < 2; ++nf) {
#pragma unroll
    for (int kk = 0; kk < 6; ++kk)
      bv[nf][kk] = *(const s16x8*)&Xs[(wid * 32 + nf * 16 + lm) * 200 + kk * 32 + lk * 8];
  }
  float* const ob = out + (size_t)b * 12582912;
  const int hq_base = hs >> 2;
  const int wq_base = (hs & 3) << 4;

#pragma unroll 1
  for (int mt = 0; mt < 3; ++mt) {
    f32x4 acc[4][2];
#pragma unroll
    for (int i = 0; i < 4; ++i) {
      acc[i][0] = f32x4{0.f, 0.f, 0.f, 0.f};
      acc[i][1] = f32x4{0.f, 0.f, 0.f, 0.f};
    }
#pragma unroll
    for (int kk = 0; kk < 6; ++kk) {
      s16x8 af[4];
#pragma unroll
      for (int mf = 0; mf < 4; ++mf)
        af[mf] = *(const s16x8*)&wp[(size_t)(mt * 64 + mf * 16 + lm) * 192 + kk * 32 + lk * 8];
#pragma unroll
      for (int mf = 0; mf < 4; ++mf) {
#pragma unroll
        for (int nf = 0; nf < 2; ++nf)
          acc[mf][nf] = __builtin_amdgcn_mfma_f32_16x16x32_bf16(af[mf], bv[nf][kk], acc[mf][nf], 0, 0, 0);
      }
    }
    __syncthreads();   // prior LDS reads (bv hoist / prior epilogue) complete
#pragma unroll
    for (int mf = 0; mf < 4; ++mf) {
#pragma unroll
      for (int nf = 0; nf < 2; ++nf) {
        const int n = wid * 32 + nf * 16 + lm;
        const int m0 = mf * 16 + lk * 4;
#pragma unroll
        for (int rr = 0; rr < 4; ++rr)
          OutF[n * 67 + m0 + rr] = acc[mf][nf][rr];
      }
    }
    __syncthreads();
#pragma unroll
    for (int tt = 0; tt < 2; ++tt) {
      const int id = tt * 512 + t;
      const int r = id & 15;
      const int m = id >> 4;                         // [0,64)
      const int co = mt * 64 + m;
      const int hqr = ((r >> 2) & 3) * 64 + hq_base;
      const int wq0 = (r & 3) * 64 + wq_base;
      float* dst = ob + (size_t)co * 65536 + (size_t)hqr * 256 + wq0;
#pragma unroll
      for (int jj = 0; jj < 16; jj += 4) {
        float4 vv = make_float4(OutF[(16 * (jj + 0) + r) * 67 + m],
                                OutF[(16 * (jj + 1) + r) * 67 + m],
                                OutF[(16 * (jj + 2) + r) * 67 + m],
                                OutF[(16 * (jj + 3) + r) * 67 + m]);
        *(float4*)(dst + jj) = vv;
      }
    }
  }
}

extern "C" void kernel_launch(void* const* d_in, const int* in_sizes, int n_in,
                              void* d_out, int out_size, void* d_ws, size_t ws_size,
                              hipStream_t stream) {
  const float* x   = (const float*)d_in[0];
  const float* wq  = (const float*)d_in[1];
  const float* wdw = (const float*)d_in[2];
  const float* wpr = (const float*)d_in[3];
  float* out = (float*)d_out;
  u16* ws = (u16*)d_ws;
  // layout (u16): wq_bf | wp_bf | qkv1 | R2
  // R2: xs (dead after k_qkv) -> qkvb (k_dw out). attnb aliases qkv1.
  u16* wq_bf = ws;
  u16* wp_bf = ws + 110592;
  u16* qkv1  = ws + 147456;                       // 4*576*65536 bf16
  u16* R2    = qkv1 + (size_t)150994944;
  u16* xs    = R2;                                // 4*65536*192 bf16
  u16* qkvb  = R2;
  u16* attnb = qkv1;

  hipLaunchKernelGGL(k_wcvt, dim3(432), dim3(256), 0, stream, wq, wpr, wq_bf, wp_bf);
  hipLaunchKernelGGL(k_shuf, dim3(512, 4), dim3(512), 0, stream, x, xs);
  hipLaunchKernelGGL(k_qkv,  dim3(512, 4), dim3(256), 0, stream, xs, wq_bf, qkv1);
  hipLaunchKernelGGL(k_dw,   dim3(32, 576, 4), dim3(256), 0, stream, qkv1, wdw, qkvb);
  hipLaunchKernelGGL(k_msa,  dim3(512, 4), dim3(256), 0, stream, qkvb, attnb);
  hipLaunchKernelGGL(k_proj, dim3(256, 4), dim3(512), 0, stream, attnb, wp_bf, out);
}

// Round 8
// 701.865 us; speedup vs baseline: 1.7007x; 1.1476x over previous
//
#include <hip/hip_runtime.h>

typedef unsigned short u16;
typedef unsigned int   u32;
typedef __attribute__((ext_vector_type(8))) short s16x8;   // 8 x bf16 MFMA frag
typedef __attribute__((ext_vector_type(4))) float f32x4;

__device__ __forceinline__ u16 f2bf(float f) {
  u32 u = __builtin_bit_cast(u32, f);
  return (u16)((u + 0x7FFFu + ((u >> 16) & 1u)) >> 16);   // RNE
}
__device__ __forceinline__ float bf2f(u16 h) {
  return __builtin_bit_cast(float, (u32)h << 16);
}
__device__ __forceinline__ u32 pack2(float a, float b) {
  return (u32)f2bf(a) | ((u32)f2bf(b) << 16);
}

// ---------------- K0: weight f32 -> bf16 ----------------
__global__ __launch_bounds__(256) void k_wcvt(const float* __restrict__ wq,
                                              const float* __restrict__ wp,
                                              u16* __restrict__ wq_bf,
                                              u16* __restrict__ wp_bf) {
  int i = blockIdx.x * 256 + threadIdx.x;
  if (i < 576 * 192) wq_bf[i] = f2bf(wq[i]);
  if (i < 192 * 192) wp_bf[i] = f2bf(wp[i]);
}

// ---------------- K1: qkv 1x1 conv (GEMM M=576,K=192), direct from x -------
// Block = one shuffled row (256 px), 256 thr = 4 waves x 64 px. sigma^-1
// gather -> Xs (one barrier; 24 iters x 256 thr = full 6144 units), av[4][6]
// hoisted (96 VGPR), wf double-buffered from L2 (4 MFMA per W-load),
// swapped-operand MFMA -> direct uint2 NCHW stores (R6-verified).
// Zero barriers in the mt loop.
__global__ __launch_bounds__(256, 1) void k_qkv(const float* __restrict__ x,
                                                const u16* __restrict__ wq,
                                                u16* __restrict__ qkv1) {
  __shared__ __align__(16) u16 Xs[256 * 200];        // [n=256][k=192 pad 200]
  const int t  = threadIdx.x;
  const int b  = blockIdx.y;
  const int h1 = blockIdx.x;
  const float* xb = x + (size_t)b * 12582912;
  const int hbase = h1 >> 2;
  const int wbase = (h1 & 3) << 4;
  // gather: run r holds px n = 16j + r at (ho(r), wo(r)+j); 64B-run loads
#pragma unroll 8
  for (int it = 0; it < 24; ++it) {
    const int idx = it * 256 + t;          // 6144 units: f(4) x r(16) x c2(96)
    const int f = idx & 3;                 // float4 within 64B run
    const int r = (idx >> 2) & 15;         // run id
    const int c = (idx >> 6) * 2;          // even channel 0..190
    const int ho = ((r >> 2) & 3) * 64 + hbase;
    const int wo = (r & 3) * 64 + wbase + f * 4;
    const float* s0 = xb + (size_t)c * 65536 + (size_t)ho * 256 + wo;
    float4 v0 = *(const float4*)s0;
    float4 v1 = *(const float4*)(s0 + 65536);
    const int nb = 64 * f + r;             // n = nb + 16q
    *(u32*)&Xs[(nb     ) * 200 + c] = pack2(v0.x, v1.x);
    *(u32*)&Xs[(nb + 16) * 200 + c] = pack2(v0.y, v1.y);
    *(u32*)&Xs[(nb + 32) * 200 + c] = pack2(v0.z, v1.z);
    *(u32*)&Xs[(nb + 48) * 200 + c] = pack2(v0.w, v1.w);
  }
  __syncthreads();
  const int lane = t & 63, wid = t >> 6;   // 4 waves x 64 px
  const int lm = lane & 15, lk = lane >> 4;
  // A-frags: px rows, hoisted once (96 VGPR)
  s16x8 av[4][6];
#pragma unroll
  for (int f = 0; f < 4; ++f) {
#pragma unroll
    for (int kk = 0; kk < 6; ++kk)
      av[f][kk] = *(const s16x8*)&Xs[(wid * 64 + f * 16 + lm) * 200 + kk * 32 + lk * 8];
  }
  u16* const ob = qkv1 + (size_t)b * 37748736 + h1 * 256 + wid * 64 + lk * 4;
  const u16* const wrow = wq + (size_t)lm * 192 + lk * 8;

#pragma unroll 1
  for (int mt = 0; mt < 9; ++mt) {
    const u16* wmt = wrow + (size_t)mt * 64 * 192;
    f32x4 acc[4][4];                        // [mf][f]
#pragma unroll
    for (int i = 0; i < 4; ++i) {
#pragma unroll
      for (int j = 0; j < 4; ++j) acc[i][j] = f32x4{0.f, 0.f, 0.f, 0.f};
    }
    s16x8 wf0[4], wf1[4];
#pragma unroll
    for (int mf = 0; mf < 4; ++mf)
      wf0[mf] = *(const s16x8*)(wmt + mf * 3072);
#pragma unroll
    for (int kk = 0; kk < 6; ++kk) {
      if ((kk & 1) == 0) {
        if (kk < 5) {
#pragma unroll
          for (int mf = 0; mf < 4; ++mf)
            wf1[mf] = *(const s16x8*)(wmt + (kk + 1) * 32 + mf * 3072);
        }
#pragma unroll
        for (int mf = 0; mf < 4; ++mf) {
#pragma unroll
          for (int f = 0; f < 4; ++f)
            acc[mf][f] = __builtin_amdgcn_mfma_f32_16x16x32_bf16(av[f][kk], wf0[mf], acc[mf][f], 0, 0, 0);
        }
      } else {
        if (kk < 5) {
#pragma unroll
          for (int mf = 0; mf < 4; ++mf)
            wf0[mf] = *(const s16x8*)(wmt + (kk + 1) * 32 + mf * 3072);
        }
#pragma unroll
        for (int mf = 0; mf < 4; ++mf) {
#pragma unroll
          for (int f = 0; f < 4; ++f)
            acc[mf][f] = __builtin_amdgcn_mfma_f32_16x16x32_bf16(av[f][kk], wf1[mf], acc[mf][f], 0, 0, 0);
        }
      }
    }
    // direct NCHW stores: lane owns px = base+f*16+lk*4..+3 of ch = mt*64+mf*16+lm
#pragma unroll
    for (int mf = 0; mf < 4; ++mf) {
      u16* dstc = ob + (size_t)(mt * 64 + mf * 16 + lm) * 65536;
#pragma unroll
      for (int f = 0; f < 4; ++f) {
        uint2 o;
        o.x = pack2(acc[mf][f][0], acc[mf][f][1]);
        o.y = pack2(acc[mf][f][2], acc[mf][f][3]);
        *(uint2*)(dstc + f * 16) = o;
      }
    }
  }
}

// ---------------- K2: depthwise 3x3, pad 1, NCHW bf16 -> NCHW bf16 --------
__global__ __launch_bounds__(256) void k_dw(const u16* __restrict__ qkv1,
                                            const float* __restrict__ wdw,
                                            u16* __restrict__ qkvb) {
  const int t = threadIdx.x;
  const int c = blockIdx.y;
  const int b = blockIdx.z;
  const int s0 = (blockIdx.x * 256 + t) * 8;
  const int h0 = s0 >> 8, w0 = s0 & 255;
  const size_t cb = ((size_t)b * 576 + c) * 65536;
  const u16* in = qkv1 + cb;
  float w9[9];
#pragma unroll
  for (int i = 0; i < 9; ++i) w9[i] = wdw[c * 9 + i];
  float acc[8] = {0.f,0.f,0.f,0.f,0.f,0.f,0.f,0.f};
#pragma unroll
  for (int ky = 0; ky < 3; ++ky) {
    const int nh = h0 + ky - 1;
    if (nh < 0 || nh > 255) continue;
    const u16* row = in + (size_t)nh * 256 + w0;
    uint4 mid = *(const uint4*)row;
    float e[10];
    e[0] = (w0 > 0) ? bf2f(row[-1]) : 0.f;
    u32 uu[4] = {mid.x, mid.y, mid.z, mid.w};
#pragma unroll
    for (int q = 0; q < 4; ++q) {
      e[1 + 2 * q] = bf2f((u16)(uu[q] & 0xffffu));
      e[2 + 2 * q] = bf2f((u16)(uu[q] >> 16));
    }
    e[9] = (w0 < 248) ? bf2f(row[8]) : 0.f;
#pragma unroll
    for (int kx = 0; kx < 3; ++kx) {
      const float wk = w9[ky * 3 + kx];
#pragma unroll
      for (int j = 0; j < 8; ++j) acc[j] += wk * e[j + kx];
    }
  }
  u32 o[4];
#pragma unroll
  for (int q = 0; q < 4; ++q)
    o[q] = pack2(acc[2 * q], acc[2 * q + 1]);
  *(uint4*)(qkvb + cb + s0) = make_uint4(o[0], o[1], o[2], o[3]);
}

// ---------------- K3: raw-reshape windowed MSA ----------------------------
__global__ __launch_bounds__(256) void k_msa(const u16* __restrict__ qkvb,
                                             u16* __restrict__ attnb) {
  const int t = threadIdx.x;
  const int b = blockIdx.y;
  const int g = blockIdx.x * 32 + (t >> 3);
  const int head = t & 7;
  const int gh = g >> 7, gw = g & 127;
  const u16* qb = qkvb + (size_t)b * 37748736;
  u16* ab = attnb + (size_t)b * 12582912;
  int poff[4];
#pragma unroll
  for (int tt = 0; tt < 4; ++tt)
    poff[tt] = (2 * gh + (tt >> 1)) * 256 + 2 * gw + (tt & 1);
  uint4 kreg[4][3], vreg[4][3];
#pragma unroll
  for (int tt = 0; tt < 4; ++tt) {
    const u16* sp = qb + (size_t)poff[tt] * 576 + head * 24;
#pragma unroll
    for (int cc = 0; cc < 3; ++cc) {
      kreg[tt][cc] = *(const uint4*)(sp + 192 + cc * 8);
      vreg[tt][cc] = *(const uint4*)(sp + 384 + cc * 8);
    }
  }
#pragma unroll
  for (int tq = 0; tq < 4; ++tq) {
    const u16* sp = qb + (size_t)poff[tq] * 576 + head * 24;
    float qf[24];
#pragma unroll
    for (int cc = 0; cc < 3; ++cc) {
      uint4 v = *(const uint4*)(sp + cc * 8);
      u32 uu[4] = {v.x, v.y, v.z, v.w};
#pragma unroll
      for (int q = 0; q < 4; ++q) {
        qf[cc * 8 + 2 * q]     = bf2f((u16)(uu[q] & 0xffffu));
        qf[cc * 8 + 2 * q + 1] = bf2f((u16)(uu[q] >> 16));
      }
    }
    float s[4];
#pragma unroll
    for (int tk = 0; tk < 4; ++tk) {
      float d = 0.f;
#pragma unroll
      for (int cc = 0; cc < 3; ++cc) {
        uint4 v = kreg[tk][cc];
        u32 uu[4] = {v.x, v.y, v.z, v.w};
#pragma unroll
        for (int q = 0; q < 4; ++q) {
          d += qf[cc * 8 + 2 * q]     * bf2f((u16)(uu[q] & 0xffffu));
          d += qf[cc * 8 + 2 * q + 1] * bf2f((u16)(uu[q] >> 16));
        }
      }
      s[tk] = d * 0.35355339059327373f;   // SCALE = HEADS^-0.5
    }
    float mx = fmaxf(fmaxf(s[0], s[1]), fmaxf(s[2], s[3]));
    float e0 = __expf(s[0] - mx), e1 = __expf(s[1] - mx);
    float e2 = __expf(s[2] - mx), e3 = __expf(s[3] - mx);
    float inv = 1.f / (e0 + e1 + e2 + e3);
    float aw[4] = {e0 * inv, e1 * inv, e2 * inv, e3 * inv};
    float of[24];
#pragma unroll
    for (int dd = 0; dd < 24; ++dd) of[dd] = 0.f;
#pragma unroll
    for (int tk = 0; tk < 4; ++tk) {
#pragma unroll
      for (int cc = 0; cc < 3; ++cc) {
        uint4 v = vreg[tk][cc];
        u32 uu[4] = {v.x, v.y, v.z, v.w};
#pragma unroll
        for (int q = 0; q < 4; ++q) {
          of[cc * 8 + 2 * q]     += aw[tk] * bf2f((u16)(uu[q] & 0xffffu));
          of[cc * 8 + 2 * q + 1] += aw[tk] * bf2f((u16)(uu[q] >> 16));
        }
      }
    }
    u16* dst = ab + (size_t)poff[tq] * 192 + head * 24;
#pragma unroll
    for (int cc = 0; cc < 3; ++cc) {
      u32 o0 = pack2(of[cc * 8 + 0], of[cc * 8 + 1]);
      u32 o1 = pack2(of[cc * 8 + 2], of[cc * 8 + 3]);
      u32 o2 = pack2(of[cc * 8 + 4], of[cc * 8 + 5]);
      u32 o3 = pack2(of[cc * 8 + 6], of[cc * 8 + 7]);
      *(uint4*)(dst + cc * 8) = make_uint4(o0, o1, o2, o3);
    }
  }
}

// ---------------- K4: proj 1x1 (GEMM M=192,K=192) + shuffle_back ----------
__global__ __launch_bounds__(512) void k_proj(const u16* __restrict__ attnb,
                                              const u16* __restrict__ wp,
                                              float* __restrict__ out) {
  __shared__ __align__(16) u16 XsRaw[256 * 200];   // 102400 B; reused OutF[256][67] f32
  u16* Xs = XsRaw;
  float* OutF = (float*)XsRaw;
  const int t  = threadIdx.x;
  const int b  = blockIdx.y;
  const int hs = blockIdx.x;
  const int pix = t & 255, cg = t >> 8;
  {
    const u16* ab = attnb + (size_t)b * 12582912 + (size_t)hs * 256 + pix;
    u16* xrow = &Xs[pix * 200];
#pragma unroll 8
    for (int i = 0; i < 96; i += 2) {
      const int c = cg * 96 + i;
      u16 v0 = ab[(size_t)c * 65536];
      u16 v1 = ab[(size_t)(c + 1) * 65536];
      *(u32*)&xrow[c] = (u32)v0 | ((u32)v1 << 16);
    }
  }
  __syncthreads();
  const int lane = t & 63, wid = t >> 6;
  const int lm = lane & 15, lk = lane >> 4;
  s16x8 bv[2][6];
#pragma unroll
  for (int nf = 0; nf < 2; ++nf) {
#pragma unroll
    for (int kk = 0; kk < 6; ++kk)
      bv[nf][kk] = *(const s16x8*)&Xs[(wid * 32 + nf * 16 + lm) * 200 + kk * 32 + lk * 8];
  }
  float* const ob = out + (size_t)b * 12582912;
  const int hq_base = hs >> 2;
  const int wq_base = (hs & 3) << 4;

#pragma unroll 1
  for (int mt = 0; mt < 3; ++mt) {
    f32x4 acc[4][2];
#pragma unroll
    for (int i = 0; i < 4; ++i) {
      acc[i][0] = f32x4{0.f, 0.f, 0.f, 0.f};
      acc[i][1] = f32x4{0.f, 0.f, 0.f, 0.f};
    }
#pragma unroll
    for (int kk = 0; kk < 6; ++kk) {
      s16x8 af[4];
#pragma unroll
      for (int mf = 0; mf < 4; ++mf)
        af[mf] = *(const s16x8*)&wp[(size_t)(mt * 64 + mf * 16 + lm) * 192 + kk * 32 + lk * 8];
#pragma unroll
      for (int mf = 0; mf < 4; ++mf) {
#pragma unroll
        for (int nf = 0; nf < 2; ++nf)
          acc[mf][nf] = __builtin_amdgcn_mfma_f32_16x16x32_bf16(af[mf], bv[nf][kk], acc[mf][nf], 0, 0, 0);
      }
    }
    __syncthreads();   // prior LDS reads (bv hoist / prior epilogue) complete
#pragma unroll
    for (int mf = 0; mf < 4; ++mf) {
#pragma unroll
      for (int nf = 0; nf < 2; ++nf) {
        const int n = wid * 32 + nf * 16 + lm;
        const int m0 = mf * 16 + lk * 4;
#pragma unroll
        for (int rr = 0; rr < 4; ++rr)
          OutF[n * 67 + m0 + rr] = acc[mf][nf][rr];
      }
    }
    __syncthreads();
#pragma unroll
    for (int tt = 0; tt < 2; ++tt) {
      const int id = tt * 512 + t;
      const int r = id & 15;
      const int m = id >> 4;                         // [0,64)
      const int co = mt * 64 + m;
      const int hqr = ((r >> 2) & 3) * 64 + hq_base;
      const int wq0 = (r & 3) * 64 + wq_base;
      float* dst = ob + (size_t)co * 65536 + (size_t)hqr * 256 + wq0;
#pragma unroll
      for (int jj = 0; jj < 16; jj += 4) {
        float4 vv = make_float4(OutF[(16 * (jj + 0) + r) * 67 + m],
                                OutF[(16 * (jj + 1) + r) * 67 + m],
                                OutF[(16 * (jj + 2) + r) * 67 + m],
                                OutF[(16 * (jj + 3) + r) * 67 + m]);
        *(float4*)(dst + jj) = vv;
      }
    }
  }
}

extern "C" void kernel_launch(void* const* d_in, const int* in_sizes, int n_in,
                              void* d_out, int out_size, void* d_ws, size_t ws_size,
                              hipStream_t stream) {
  const float* x   = (const float*)d_in[0];
  const float* wq  = (const float*)d_in[1];
  const float* wdw = (const float*)d_in[2];
  const float* wpr = (const float*)d_in[3];
  float* out = (float*)d_out;
  u16* ws = (u16*)d_ws;
  // layout (u16): wq_bf | wp_bf | qkv1 | qkvb ; attnb aliases qkv1 (dead after k_dw)
  u16* wq_bf = ws;
  u16* wp_bf = ws + 110592;
  u16* qkv1  = ws + 147456;                       // 4*576*65536 bf16 (NCHW)
  u16* qkvb  = qkv1 + (size_t)150994944;          // 4*576*65536 bf16 (NCHW)
  u16* attnb = qkv1;

  hipLaunchKernelGGL(k_wcvt, dim3(432), dim3(256), 0, stream, wq, wpr, wq_bf, wp_bf);
  hipLaunchKernelGGL(k_qkv,  dim3(256, 4), dim3(256), 0, stream, x, wq_bf, qkv1);
  hipLaunchKernelGGL(k_dw,   dim3(32, 576, 4), dim3(256), 0, stream, qkv1, wdw, qkvb);
  hipLaunchKernelGGL(k_msa,  dim3(512, 4), dim3(256), 0, stream, qkvb, attnb);
  hipLaunchKernelGGL(k_proj, dim3(256, 4), dim3(512), 0, stream, attnb, wp_bf, out);
}

// Round 9
// 597.961 us; speedup vs baseline: 1.9962x; 1.1738x over previous
//
#include <hip/hip_runtime.h>

typedef unsigned short u16;
typedef unsigned int   u32;
typedef __attribute__((ext_vector_type(8))) short s16x8;   // 8 x bf16 MFMA frag
typedef __attribute__((ext_vector_type(4))) float f32x4;

__device__ __forceinline__ u16 f2bf(float f) {
  u32 u = __builtin_bit_cast(u32, f);
  return (u16)((u + 0x7FFFu + ((u >> 16) & 1u)) >> 16);   // RNE
}
__device__ __forceinline__ float bf2f(u16 h) {
  return __builtin_bit_cast(float, (u32)h << 16);
}
__device__ __forceinline__ u32 pack2(float a, float b) {
  return (u32)f2bf(a) | ((u32)f2bf(b) << 16);
}

// ---------------- K0: weight f32 -> bf16 ----------------
__global__ __launch_bounds__(256) void k_wcvt(const float* __restrict__ wq,
                                              const float* __restrict__ wp,
                                              u16* __restrict__ wq_bf,
                                              u16* __restrict__ wp_bf) {
  int i = blockIdx.x * 256 + threadIdx.x;
  if (i < 576 * 192) wq_bf[i] = f2bf(wq[i]);
  if (i < 192 * 192) wp_bf[i] = f2bf(wp[i]);
}

// ---------------- K1: qkv 1x1 conv (GEMM M=576,K=192), W-in-registers ------
// Block = one shuffled row (256 px), 768 thr = 12 waves. Wave wv owns
// channel slice [48wv, 48wv+48): wf[3][6] (72 VGPR) loaded ONCE from L2.
// Px streamed from LDS in 16-px groups (6 ds_read + 18 MFMA + 3 uint2
// stores each). Zero barriers after gather; stores fire-and-forget.
__global__ __launch_bounds__(768, 3) void k_qkv(const float* __restrict__ x,
                                                const u16* __restrict__ wq,
                                                u16* __restrict__ qkv1) {
  __shared__ __align__(16) u16 Xs[256 * 200];        // [n=256][k=192 pad 200]
  const int t  = threadIdx.x;
  const int b  = blockIdx.y;
  const int h1 = blockIdx.x;
  const float* xb = x + (size_t)b * 12582912;
  const int hbase = h1 >> 2;
  const int wbase = (h1 & 3) << 4;
  // sigma^-1 gather: run r holds px n = 16j + r at (ho(r), wo(r)+j); 64B runs
#pragma unroll
  for (int it = 0; it < 8; ++it) {
    const int idx = it * 768 + t;          // 6144 units: f(4) x r(16) x c2(96)
    const int f = idx & 3;                 // float4 within 64B run
    const int r = (idx >> 2) & 15;         // run id
    const int c = (idx >> 6) * 2;          // even channel 0..190
    const int ho = ((r >> 2) & 3) * 64 + hbase;
    const int wo = (r & 3) * 64 + wbase + f * 4;
    const float* s0 = xb + (size_t)c * 65536 + (size_t)ho * 256 + wo;
    float4 v0 = *(const float4*)s0;
    float4 v1 = *(const float4*)(s0 + 65536);
    const int nb = 64 * f + r;             // n = nb + 16q
    *(u32*)&Xs[(nb     ) * 200 + c] = pack2(v0.x, v1.x);
    *(u32*)&Xs[(nb + 16) * 200 + c] = pack2(v0.y, v1.y);
    *(u32*)&Xs[(nb + 32) * 200 + c] = pack2(v0.z, v1.z);
    *(u32*)&Xs[(nb + 48) * 200 + c] = pack2(v0.w, v1.w);
  }
  __syncthreads();
  const int lane = t & 63, wv = t >> 6;    // 12 waves, ch slice each
  const int lm = lane & 15, lk = lane >> 4;
  // W slice -> registers, once (rows = ch, swapped-operand B frag)
  s16x8 wf[3][6];
#pragma unroll
  for (int mf = 0; mf < 3; ++mf) {
#pragma unroll
    for (int kk = 0; kk < 6; ++kk)
      wf[mf][kk] = *(const s16x8*)&wq[(size_t)(wv * 48 + mf * 16 + lm) * 192 + kk * 32 + lk * 8];
  }
  u16* const ob = qkv1 + (size_t)b * 37748736 + h1 * 256 + lk * 4;

#pragma unroll 2
  for (int g = 0; g < 16; ++g) {
    // A-frags: px rows g*16+lm
    s16x8 av[6];
#pragma unroll
    for (int kk = 0; kk < 6; ++kk)
      av[kk] = *(const s16x8*)&Xs[(g * 16 + lm) * 200 + kk * 32 + lk * 8];
    f32x4 acc[3];
#pragma unroll
    for (int mf = 0; mf < 3; ++mf) acc[mf] = f32x4{0.f, 0.f, 0.f, 0.f};
#pragma unroll
    for (int kk = 0; kk < 6; ++kk) {
#pragma unroll
      for (int mf = 0; mf < 3; ++mf)
        acc[mf] = __builtin_amdgcn_mfma_f32_16x16x32_bf16(av[kk], wf[mf][kk], acc[mf], 0, 0, 0);
    }
    // D[row=px][col=ch]: lane holds px = g*16 + lk*4 + rr, ch = wv*48+mf*16+lm
#pragma unroll
    for (int mf = 0; mf < 3; ++mf) {
      const int ch = wv * 48 + mf * 16 + lm;
      uint2 o;
      o.x = pack2(acc[mf][0], acc[mf][1]);
      o.y = pack2(acc[mf][2], acc[mf][3]);
      *(uint2*)(ob + (size_t)ch * 65536 + g * 16) = o;
    }
  }
}

// ---------------- K2: depthwise 3x3, pad 1, NCHW bf16 -> NCHW bf16 --------
__global__ __launch_bounds__(256) void k_dw(const u16* __restrict__ qkv1,
                                            const float* __restrict__ wdw,
                                            u16* __restrict__ qkvb) {
  const int t = threadIdx.x;
  const int c = blockIdx.y;
  const int b = blockIdx.z;
  const int s0 = (blockIdx.x * 256 + t) * 8;
  const int h0 = s0 >> 8, w0 = s0 & 255;
  const size_t cb = ((size_t)b * 576 + c) * 65536;
  const u16* in = qkv1 + cb;
  float w9[9];
#pragma unroll
  for (int i = 0; i < 9; ++i) w9[i] = wdw[c * 9 + i];
  float acc[8] = {0.f,0.f,0.f,0.f,0.f,0.f,0.f,0.f};
#pragma unroll
  for (int ky = 0; ky < 3; ++ky) {
    const int nh = h0 + ky - 1;
    if (nh < 0 || nh > 255) continue;
    const u16* row = in + (size_t)nh * 256 + w0;
    uint4 mid = *(const uint4*)row;
    float e[10];
    e[0] = (w0 > 0) ? bf2f(row[-1]) : 0.f;
    u32 uu[4] = {mid.x, mid.y, mid.z, mid.w};
#pragma unroll
    for (int q = 0; q < 4; ++q) {
      e[1 + 2 * q] = bf2f((u16)(uu[q] & 0xffffu));
      e[2 + 2 * q] = bf2f((u16)(uu[q] >> 16));
    }
    e[9] = (w0 < 248) ? bf2f(row[8]) : 0.f;
#pragma unroll
    for (int kx = 0; kx < 3; ++kx) {
      const float wk = w9[ky * 3 + kx];
#pragma unroll
      for (int j = 0; j < 8; ++j) acc[j] += wk * e[j + kx];
    }
  }
  u32 o[4];
#pragma unroll
  for (int q = 0; q < 4; ++q)
    o[q] = pack2(acc[2 * q], acc[2 * q + 1]);
  *(uint4*)(qkvb + cb + s0) = make_uint4(o[0], o[1], o[2], o[3]);
}

// ---------------- K3: raw-reshape windowed MSA ----------------------------
__global__ __launch_bounds__(256) void k_msa(const u16* __restrict__ qkvb,
                                             u16* __restrict__ attnb) {
  const int t = threadIdx.x;
  const int b = blockIdx.y;
  const int g = blockIdx.x * 32 + (t >> 3);
  const int head = t & 7;
  const int gh = g >> 7, gw = g & 127;
  const u16* qb = qkvb + (size_t)b * 37748736;
  u16* ab = attnb + (size_t)b * 12582912;
  int poff[4];
#pragma unroll
  for (int tt = 0; tt < 4; ++tt)
    poff[tt] = (2 * gh + (tt >> 1)) * 256 + 2 * gw + (tt & 1);
  uint4 kreg[4][3], vreg[4][3];
#pragma unroll
  for (int tt = 0; tt < 4; ++tt) {
    const u16* sp = qb + (size_t)poff[tt] * 576 + head * 24;
#pragma unroll
    for (int cc = 0; cc < 3; ++cc) {
      kreg[tt][cc] = *(const uint4*)(sp + 192 + cc * 8);
      vreg[tt][cc] = *(const uint4*)(sp + 384 + cc * 8);
    }
  }
#pragma unroll
  for (int tq = 0; tq < 4; ++tq) {
    const u16* sp = qb + (size_t)poff[tq] * 576 + head * 24;
    float qf[24];
#pragma unroll
    for (int cc = 0; cc < 3; ++cc) {
      uint4 v = *(const uint4*)(sp + cc * 8);
      u32 uu[4] = {v.x, v.y, v.z, v.w};
#pragma unroll
      for (int q = 0; q < 4; ++q) {
        qf[cc * 8 + 2 * q]     = bf2f((u16)(uu[q] & 0xffffu));
        qf[cc * 8 + 2 * q + 1] = bf2f((u16)(uu[q] >> 16));
      }
    }
    float s[4];
#pragma unroll
    for (int tk = 0; tk < 4; ++tk) {
      float d = 0.f;
#pragma unroll
      for (int cc = 0; cc < 3; ++cc) {
        uint4 v = kreg[tk][cc];
        u32 uu[4] = {v.x, v.y, v.z, v.w};
#pragma unroll
        for (int q = 0; q < 4; ++q) {
          d += qf[cc * 8 + 2 * q]     * bf2f((u16)(uu[q] & 0xffffu));
          d += qf[cc * 8 + 2 * q + 1] * bf2f((u16)(uu[q] >> 16));
        }
      }
      s[tk] = d * 0.35355339059327373f;   // SCALE = HEADS^-0.5
    }
    float mx = fmaxf(fmaxf(s[0], s[1]), fmaxf(s[2], s[3]));
    float e0 = __expf(s[0] - mx), e1 = __expf(s[1] - mx);
    float e2 = __expf(s[2] - mx), e3 = __expf(s[3] - mx);
    float inv = 1.f / (e0 + e1 + e2 + e3);
    float aw[4] = {e0 * inv, e1 * inv, e2 * inv, e3 * inv};
    float of[24];
#pragma unroll
    for (int dd = 0; dd < 24; ++dd) of[dd] = 0.f;
#pragma unroll
    for (int tk = 0; tk < 4; ++tk) {
#pragma unroll
      for (int cc = 0; cc < 3; ++cc) {
        uint4 v = vreg[tk][cc];
        u32 uu[4] = {v.x, v.y, v.z, v.w};
#pragma unroll
        for (int q = 0; q < 4; ++q) {
          of[cc * 8 + 2 * q]     += aw[tk] * bf2f((u16)(uu[q] & 0xffffu));
          of[cc * 8 + 2 * q + 1] += aw[tk] * bf2f((u16)(uu[q] >> 16));
        }
      }
    }
    u16* dst = ab + (size_t)poff[tq] * 192 + head * 24;
#pragma unroll
    for (int cc = 0; cc < 3; ++cc) {
      u32 o0 = pack2(of[cc * 8 + 0], of[cc * 8 + 1]);
      u32 o1 = pack2(of[cc * 8 + 2], of[cc * 8 + 3]);
      u32 o2 = pack2(of[cc * 8 + 4], of[cc * 8 + 5]);
      u32 o3 = pack2(of[cc * 8 + 6], of[cc * 8 + 7]);
      *(uint4*)(dst + cc * 8) = make_uint4(o0, o1, o2, o3);
    }
  }
}

// ---------------- K4: proj 1x1 (GEMM M=192,K=192) + shuffle_back ----------
__global__ __launch_bounds__(512) void k_proj(const u16* __restrict__ attnb,
                                              const u16* __restrict__ wp,
                                              float* __restrict__ out) {
  __shared__ __align__(16) u16 XsRaw[256 * 200];   // 102400 B; reused OutF[256][67] f32
  u16* Xs = XsRaw;
  float* OutF = (float*)XsRaw;
  const int t  = threadIdx.x;
  const int b  = blockIdx.y;
  const int hs = blockIdx.x;
  const int pix = t & 255, cg = t >> 8;
  {
    const u16* ab = attnb + (size_t)b * 12582912 + (size_t)hs * 256 + pix;
    u16* xrow = &Xs[pix * 200];
#pragma unroll 8
    for (int i = 0; i < 96; i += 2) {
      const int c = cg * 96 + i;
      u16 v0 = ab[(size_t)c * 65536];
      u16 v1 = ab[(size_t)(c + 1) * 65536];
      *(u32*)&xrow[c] = (u32)v0 | ((u32)v1 << 16);
    }
  }
  __syncthreads();
  const int lane = t & 63, wid = t >> 6;
  const int lm = lane & 15, lk = lane >> 4;
  s16x8 bv[2][6];
#pragma unroll
  for (int nf = 0; nf < 2; ++nf) {
#pragma unroll
    for (int kk = 0; kk < 6; ++kk)
      bv[nf][kk] = *(const s16x8*)&Xs[(wid * 32 + nf * 16 + lm) * 200 + kk * 32 + lk * 8];
  }
  float* const ob = out + (size_t)b * 12582912;
  const int hq_base = hs >> 2;
  const int wq_base = (hs & 3) << 4;

#pragma unroll 1
  for (int mt = 0; mt < 3; ++mt) {
    f32x4 acc[4][2];
#pragma unroll
    for (int i = 0; i < 4; ++i) {
      acc[i][0] = f32x4{0.f, 0.f, 0.f, 0.f};
      acc[i][1] = f32x4{0.f, 0.f, 0.f, 0.f};
    }
#pragma unroll
    for (int kk = 0; kk < 6; ++kk) {
      s16x8 af[4];
#pragma unroll
      for (int mf = 0; mf < 4; ++mf)
        af[mf] = *(const s16x8*)&wp[(size_t)(mt * 64 + mf * 16 + lm) * 192 + kk * 32 + lk * 8];
#pragma unroll
      for (int mf = 0; mf < 4; ++mf) {
#pragma unroll
        for (int nf = 0; nf < 2; ++nf)
          acc[mf][nf] = __builtin_amdgcn_mfma_f32_16x16x32_bf16(af[mf], bv[nf][kk], acc[mf][nf], 0, 0, 0);
      }
    }
    __syncthreads();   // prior LDS reads (bv hoist / prior epilogue) complete
#pragma unroll
    for (int mf = 0; mf < 4; ++mf) {
#pragma unroll
      for (int nf = 0; nf < 2; ++nf) {
        const int n = wid * 32 + nf * 16 + lm;
        const int m0 = mf * 16 + lk * 4;
#pragma unroll
        for (int rr = 0; rr < 4; ++rr)
          OutF[n * 67 + m0 + rr] = acc[mf][nf][rr];
      }
    }
    __syncthreads();
#pragma unroll
    for (int tt = 0; tt < 2; ++tt) {
      const int id = tt * 512 + t;
      const int r = id & 15;
      const int m = id >> 4;                         // [0,64)
      const int co = mt * 64 + m;
      const int hqr = ((r >> 2) & 3) * 64 + hq_base;
      const int wq0 = (r & 3) * 64 + wq_base;
      float* dst = ob + (size_t)co * 65536 + (size_t)hqr * 256 + wq0;
#pragma unroll
      for (int jj = 0; jj < 16; jj += 4) {
        float4 vv = make_float4(OutF[(16 * (jj + 0) + r) * 67 + m],
                                OutF[(16 * (jj + 1) + r) * 67 + m],
                                OutF[(16 * (jj + 2) + r) * 67 + m],
                                OutF[(16 * (jj + 3) + r) * 67 + m]);
        *(float4*)(dst + jj) = vv;
      }
    }
  }
}

extern "C" void kernel_launch(void* const* d_in, const int* in_sizes, int n_in,
                              void* d_out, int out_size, void* d_ws, size_t ws_size,
                              hipStream_t stream) {
  const float* x   = (const float*)d_in[0];
  const float* wq  = (const float*)d_in[1];
  const float* wdw = (const float*)d_in[2];
  const float* wpr = (const float*)d_in[3];
  float* out = (float*)d_out;
  u16* ws = (u16*)d_ws;
  // layout (u16): wq_bf | wp_bf | qkv1 | qkvb ; attnb aliases qkv1 (dead after k_dw)
  u16* wq_bf = ws;
  u16* wp_bf = ws + 110592;
  u16* qkv1  = ws + 147456;                       // 4*576*65536 bf16 (NCHW)
  u16* qkvb  = qkv1 + (size_t)150994944;          // 4*576*65536 bf16 (NCHW)
  u16* attnb = qkv1;

  hipLaunchKernelGGL(k_wcvt, dim3(432), dim3(256), 0, stream, wq, wpr, wq_bf, wp_bf);
  hipLaunchKernelGGL(k_qkv,  dim3(256, 4), dim3(768), 0, stream, x, wq_bf, qkv1);
  hipLaunchKernelGGL(k_dw,   dim3(32, 576, 4), dim3(256), 0, stream, qkv1, wdw, qkvb);
  hipLaunchKernelGGL(k_msa,  dim3(512, 4), dim3(256), 0, stream, qkvb, attnb);
  hipLaunchKernelGGL(k_proj, dim3(256, 4), dim3(512), 0, stream, attnb, wp_bf, out);
}

// Round 10
// 561.315 us; speedup vs baseline: 2.1266x; 1.0653x over previous
//
#include <hip/hip_runtime.h>

typedef unsigned short u16;
typedef unsigned int   u32;
typedef __attribute__((ext_vector_type(8))) short s16x8;   // 8 x bf16 MFMA frag
typedef __attribute__((ext_vector_type(4))) float f32x4;

__device__ __forceinline__ u16 f2bf(float f) {
  u32 u = __builtin_bit_cast(u32, f);
  return (u16)((u + 0x7FFFu + ((u >> 16) & 1u)) >> 16);   // RNE
}
__device__ __forceinline__ float bf2f(u16 h) {
  return __builtin_bit_cast(float, (u32)h << 16);
}
__device__ __forceinline__ u32 pack2(float a, float b) {
  return (u32)f2bf(a) | ((u32)f2bf(b) << 16);
}

// ---------------- K0: weight f32 -> bf16 ----------------
__global__ __launch_bounds__(256) void k_wcvt(const float* __restrict__ wq,
                                              const float* __restrict__ wp,
                                              u16* __restrict__ wq_bf,
                                              u16* __restrict__ wp_bf) {
  int i = blockIdx.x * 256 + threadIdx.x;
  if (i < 576 * 192) wq_bf[i] = f2bf(wq[i]);
  if (i < 192 * 192) wp_bf[i] = f2bf(wp[i]);
}

// ---------------- K1: qkv 1x1 conv (GEMM M=576,K=192), W-in-registers ------
// (R9-verified: 12 waves, wf[3][6] loaded once, zero barriers after gather.)
__global__ __launch_bounds__(768, 3) void k_qkv(const float* __restrict__ x,
                                                const u16* __restrict__ wq,
                                                u16* __restrict__ qkv1) {
  __shared__ __align__(16) u16 Xs[256 * 200];        // [n=256][k=192 pad 200]
  const int t  = threadIdx.x;
  const int b  = blockIdx.y;
  const int h1 = blockIdx.x;
  const float* xb = x + (size_t)b * 12582912;
  const int hbase = h1 >> 2;
  const int wbase = (h1 & 3) << 4;
#pragma unroll
  for (int it = 0; it < 8; ++it) {
    const int idx = it * 768 + t;          // 6144 units: f(4) x r(16) x c2(96)
    const int f = idx & 3;
    const int r = (idx >> 2) & 15;
    const int c = (idx >> 6) * 2;
    const int ho = ((r >> 2) & 3) * 64 + hbase;
    const int wo = (r & 3) * 64 + wbase + f * 4;
    const float* s0 = xb + (size_t)c * 65536 + (size_t)ho * 256 + wo;
    float4 v0 = *(const float4*)s0;
    float4 v1 = *(const float4*)(s0 + 65536);
    const int nb = 64 * f + r;
    *(u32*)&Xs[(nb     ) * 200 + c] = pack2(v0.x, v1.x);
    *(u32*)&Xs[(nb + 16) * 200 + c] = pack2(v0.y, v1.y);
    *(u32*)&Xs[(nb + 32) * 200 + c] = pack2(v0.z, v1.z);
    *(u32*)&Xs[(nb + 48) * 200 + c] = pack2(v0.w, v1.w);
  }
  __syncthreads();
  const int lane = t & 63, wv = t >> 6;    // 12 waves, ch slice each
  const int lm = lane & 15, lk = lane >> 4;
  s16x8 wf[3][6];
#pragma unroll
  for (int mf = 0; mf < 3; ++mf) {
#pragma unroll
    for (int kk = 0; kk < 6; ++kk)
      wf[mf][kk] = *(const s16x8*)&wq[(size_t)(wv * 48 + mf * 16 + lm) * 192 + kk * 32 + lk * 8];
  }
  u16* const ob = qkv1 + (size_t)b * 37748736 + h1 * 256 + lk * 4;

#pragma unroll 2
  for (int g = 0; g < 16; ++g) {
    s16x8 av[6];
#pragma unroll
    for (int kk = 0; kk < 6; ++kk)
      av[kk] = *(const s16x8*)&Xs[(g * 16 + lm) * 200 + kk * 32 + lk * 8];
    f32x4 acc[3];
#pragma unroll
    for (int mf = 0; mf < 3; ++mf) acc[mf] = f32x4{0.f, 0.f, 0.f, 0.f};
#pragma unroll
    for (int kk = 0; kk < 6; ++kk) {
#pragma unroll
      for (int mf = 0; mf < 3; ++mf)
        acc[mf] = __builtin_amdgcn_mfma_f32_16x16x32_bf16(av[kk], wf[mf][kk], acc[mf], 0, 0, 0);
    }
#pragma unroll
    for (int mf = 0; mf < 3; ++mf) {
      const int ch = wv * 48 + mf * 16 + lm;
      uint2 o;
      o.x = pack2(acc[mf][0], acc[mf][1]);
      o.y = pack2(acc[mf][2], acc[mf][3]);
      *(uint2*)(ob + (size_t)ch * 65536 + g * 16) = o;
    }
  }
}

// ---------------- K2: depthwise 3x3, pad 1, NCHW bf16 -> NCHW bf16 --------
// ILP rewrite: all 9 loads issued unconditionally up front (clamped row
// pointers, per-lane cndmask addressing, no branches); invalid rows are
// zeroed via their 3 WEIGHTS, not their 10 pixels.
__global__ __launch_bounds__(256) void k_dw(const u16* __restrict__ qkv1,
                                            const float* __restrict__ wdw,
                                            u16* __restrict__ qkvb) {
  const int t = threadIdx.x;
  const int c = blockIdx.y;
  const int b = blockIdx.z;
  const int s0 = (blockIdx.x * 256 + t) * 8;
  const int h0 = s0 >> 8, w0 = s0 & 255;
  const size_t cb = ((size_t)b * 576 + c) * 65536;
  const u16* in = qkv1 + cb;
  const int hm = (h0 > 0)   ? h0 - 1 : 0;
  const int hp = (h0 < 255) ? h0 + 1 : 255;
  const u16* rowm = in + (size_t)hm * 256 + w0;
  const u16* rowc = in + (size_t)h0 * 256 + w0;
  const u16* rowp = in + (size_t)hp * 256 + w0;
  const int loff = (w0 > 0) ? -1 : 0;       // clamped edge offsets
  const int roff = (w0 < 248) ? 8 : 7;
  // ---- issue all 9 loads back-to-back ----
  uint4 m0 = *(const uint4*)rowm;
  uint4 m1 = *(const uint4*)rowc;
  uint4 m2 = *(const uint4*)rowp;
  u16 lr0 = rowm[loff], rr0 = rowm[roff];
  u16 lr1 = rowc[loff], rr1 = rowc[roff];
  u16 lr2 = rowp[loff], rr2 = rowp[roff];
  // ---- weights (invalid rows / edges zeroed via weights & value masks) ----
  const float vm = (h0 > 0)   ? 1.f : 0.f;
  const float vp = (h0 < 255) ? 1.f : 0.f;
  float w9[9];
#pragma unroll
  for (int i = 0; i < 9; ++i) w9[i] = wdw[c * 9 + i];
  w9[0] *= vm; w9[1] *= vm; w9[2] *= vm;
  w9[6] *= vp; w9[7] *= vp; w9[8] *= vp;
  const float lmask = (w0 > 0) ? 1.f : 0.f;
  const float rmask = (w0 < 248) ? 1.f : 0.f;
  float acc[8] = {0.f,0.f,0.f,0.f,0.f,0.f,0.f,0.f};
  const uint4 mids[3] = {m0, m1, m2};
  const u16 lrs[3] = {lr0, lr1, lr2};
  const u16 rrs[3] = {rr0, rr1, rr2};
#pragma unroll
  for (int ky = 0; ky < 3; ++ky) {
    float e[10];
    e[0] = bf2f(lrs[ky]) * lmask;
    u32 uu[4] = {mids[ky].x, mids[ky].y, mids[ky].z, mids[ky].w};
#pragma unroll
    for (int q = 0; q < 4; ++q) {
      e[1 + 2 * q] = bf2f((u16)(uu[q] & 0xffffu));
      e[2 + 2 * q] = bf2f((u16)(uu[q] >> 16));
    }
    e[9] = bf2f(rrs[ky]) * rmask;
#pragma unroll
    for (int kx = 0; kx < 3; ++kx) {
      const float wk = w9[ky * 3 + kx];
#pragma unroll
      for (int j = 0; j < 8; ++j) acc[j] += wk * e[j + kx];
    }
  }
  u32 o[4];
#pragma unroll
  for (int q = 0; q < 4; ++q)
    o[q] = pack2(acc[2 * q], acc[2 * q + 1]);
  *(uint4*)(qkvb + cb + s0) = make_uint4(o[0], o[1], o[2], o[3]);
}

// ---------------- K3: raw-reshape windowed MSA ----------------------------
__global__ __launch_bounds__(256) void k_msa(const u16* __restrict__ qkvb,
                                             u16* __restrict__ attnb) {
  const int t = threadIdx.x;
  const int b = blockIdx.y;
  const int g = blockIdx.x * 32 + (t >> 3);
  const int head = t & 7;
  const int gh = g >> 7, gw = g & 127;
  const u16* qb = qkvb + (size_t)b * 37748736;
  u16* ab = attnb + (size_t)b * 12582912;
  int poff[4];
#pragma unroll
  for (int tt = 0; tt < 4; ++tt)
    poff[tt] = (2 * gh + (tt >> 1)) * 256 + 2 * gw + (tt & 1);
  uint4 kreg[4][3], vreg[4][3];
#pragma unroll
  for (int tt = 0; tt < 4; ++tt) {
    const u16* sp = qb + (size_t)poff[tt] * 576 + head * 24;
#pragma unroll
    for (int cc = 0; cc < 3; ++cc) {
      kreg[tt][cc] = *(const uint4*)(sp + 192 + cc * 8);
      vreg[tt][cc] = *(const uint4*)(sp + 384 + cc * 8);
    }
  }
#pragma unroll
  for (int tq = 0; tq < 4; ++tq) {
    const u16* sp = qb + (size_t)poff[tq] * 576 + head * 24;
    float qf[24];
#pragma unroll
    for (int cc = 0; cc < 3; ++cc) {
      uint4 v = *(const uint4*)(sp + cc * 8);
      u32 uu[4] = {v.x, v.y, v.z, v.w};
#pragma unroll
      for (int q = 0; q < 4; ++q) {
        qf[cc * 8 + 2 * q]     = bf2f((u16)(uu[q] & 0xffffu));
        qf[cc * 8 + 2 * q + 1] = bf2f((u16)(uu[q] >> 16));
      }
    }
    float s[4];
#pragma unroll
    for (int tk = 0; tk < 4; ++tk) {
      float d = 0.f;
#pragma unroll
      for (int cc = 0; cc < 3; ++cc) {
        uint4 v = kreg[tk][cc];
        u32 uu[4] = {v.x, v.y, v.z, v.w};
#pragma unroll
        for (int q = 0; q < 4; ++q) {
          d += qf[cc * 8 + 2 * q]     * bf2f((u16)(uu[q] & 0xffffu));
          d += qf[cc * 8 + 2 * q + 1] * bf2f((u16)(uu[q] >> 16));
        }
      }
      s[tk] = d * 0.35355339059327373f;   // SCALE = HEADS^-0.5
    }
    float mx = fmaxf(fmaxf(s[0], s[1]), fmaxf(s[2], s[3]));
    float e0 = __expf(s[0] - mx), e1 = __expf(s[1] - mx);
    float e2 = __expf(s[2] - mx), e3 = __expf(s[3] - mx);
    float inv = 1.f / (e0 + e1 + e2 + e3);
    float aw[4] = {e0 * inv, e1 * inv, e2 * inv, e3 * inv};
    float of[24];
#pragma unroll
    for (int dd = 0; dd < 24; ++dd) of[dd] = 0.f;
#pragma unroll
    for (int tk = 0; tk < 4; ++tk) {
#pragma unroll
      for (int cc = 0; cc < 3; ++cc) {
        uint4 v = vreg[tk][cc];
        u32 uu[4] = {v.x, v.y, v.z, v.w};
#pragma unroll
        for (int q = 0; q < 4; ++q) {
          of[cc * 8 + 2 * q]     += aw[tk] * bf2f((u16)(uu[q] & 0xffffu));
          of[cc * 8 + 2 * q + 1] += aw[tk] * bf2f((u16)(uu[q] >> 16));
        }
      }
    }
    u16* dst = ab + (size_t)poff[tq] * 192 + head * 24;
#pragma unroll
    for (int cc = 0; cc < 3; ++cc) {
      u32 o0 = pack2(of[cc * 8 + 0], of[cc * 8 + 1]);
      u32 o1 = pack2(of[cc * 8 + 2], of[cc * 8 + 3]);
      u32 o2 = pack2(of[cc * 8 + 4], of[cc * 8 + 5]);
      u32 o3 = pack2(of[cc * 8 + 6], of[cc * 8 + 7]);
      *(uint4*)(dst + cc * 8) = make_uint4(o0, o1, o2, o3);
    }
  }
}

// ---------------- K4: proj 1x1 (GEMM M=192,K=192) + shuffle_back ----------
__global__ __launch_bounds__(512) void k_proj(const u16* __restrict__ attnb,
                                              const u16* __restrict__ wp,
                                              float* __restrict__ out) {
  __shared__ __align__(16) u16 XsRaw[256 * 200];   // 102400 B; reused OutF[256][67] f32
  u16* Xs = XsRaw;
  float* OutF = (float*)XsRaw;
  const int t  = threadIdx.x;
  const int b  = blockIdx.y;
  const int hs = blockIdx.x;
  const int pix = t & 255, cg = t >> 8;
  {
    const u16* ab = attnb + (size_t)b * 12582912 + (size_t)hs * 256 + pix;
    u16* xrow = &Xs[pix * 200];
#pragma unroll 8
    for (int i = 0; i < 96; i += 2) {
      const int c = cg * 96 + i;
      u16 v0 = ab[(size_t)c * 65536];
      u16 v1 = ab[(size_t)(c + 1) * 65536];
      *(u32*)&xrow[c] = (u32)v0 | ((u32)v1 << 16);
    }
  }
  __syncthreads();
  const int lane = t & 63, wid = t >> 6;
  const int lm = lane & 15, lk = lane >> 4;
  s16x8 bv[2][6];
#pragma unroll
  for (int nf = 0; nf < 2; ++nf) {
#pragma unroll
    for (int kk = 0; kk < 6; ++kk)
      bv[nf][kk] = *(const s16x8*)&Xs[(wid * 32 + nf * 16 + lm) * 200 + kk * 32 + lk * 8];
  }
  float* const ob = out + (size_t)b * 12582912;
  const int hq_base = hs >> 2;
  const int wq_base = (hs & 3) << 4;

#pragma unroll 1
  for (int mt = 0; mt < 3; ++mt) {
    f32x4 acc[4][2];
#pragma unroll
    for (int i = 0; i < 4; ++i) {
      acc[i][0] = f32x4{0.f, 0.f, 0.f, 0.f};
      acc[i][1] = f32x4{0.f, 0.f, 0.f, 0.f};
    }
#pragma unroll
    for (int kk = 0; kk < 6; ++kk) {
      s16x8 af[4];
#pragma unroll
      for (int mf = 0; mf < 4; ++mf)
        af[mf] = *(const s16x8*)&wp[(size_t)(mt * 64 + mf * 16 + lm) * 192 + kk * 32 + lk * 8];
#pragma unroll
      for (int mf = 0; mf < 4; ++mf) {
#pragma unroll
        for (int nf = 0; nf < 2; ++nf)
          acc[mf][nf] = __builtin_amdgcn_mfma_f32_16x16x32_bf16(af[mf], bv[nf][kk], acc[mf][nf], 0, 0, 0);
      }
    }
    __syncthreads();   // prior LDS reads (bv hoist / prior epilogue) complete
#pragma unroll
    for (int mf = 0; mf < 4; ++mf) {
#pragma unroll
      for (int nf = 0; nf < 2; ++nf) {
        const int n = wid * 32 + nf * 16 + lm;
        const int m0 = mf * 16 + lk * 4;
#pragma unroll
        for (int rr = 0; rr < 4; ++rr)
          OutF[n * 67 + m0 + rr] = acc[mf][nf][rr];
      }
    }
    __syncthreads();
#pragma unroll
    for (int tt = 0; tt < 2; ++tt) {
      const int id = tt * 512 + t;
      const int r = id & 15;
      const int m = id >> 4;                         // [0,64)
      const int co = mt * 64 + m;
      const int hqr = ((r >> 2) & 3) * 64 + hq_base;
      const int wq0 = (r & 3) * 64 + wq_base;
      float* dst = ob + (size_t)co * 65536 + (size_t)hqr * 256 + wq0;
#pragma unroll
      for (int jj = 0; jj < 16; jj += 4) {
        float4 vv = make_float4(OutF[(16 * (jj + 0) + r) * 67 + m],
                                OutF[(16 * (jj + 1) + r) * 67 + m],
                                OutF[(16 * (jj + 2) + r) * 67 + m],
                                OutF[(16 * (jj + 3) + r) * 67 + m]);
        *(float4*)(dst + jj) = vv;
      }
    }
  }
}

extern "C" void kernel_launch(void* const* d_in, const int* in_sizes, int n_in,
                              void* d_out, int out_size, void* d_ws, size_t ws_size,
                              hipStream_t stream) {
  const float* x   = (const float*)d_in[0];
  const float* wq  = (const float*)d_in[1];
  const float* wdw = (const float*)d_in[2];
  const float* wpr = (const float*)d_in[3];
  float* out = (float*)d_out;
  u16* ws = (u16*)d_ws;
  // layout (u16): wq_bf | wp_bf | qkv1 | qkvb ; attnb aliases qkv1 (dead after k_dw)
  u16* wq_bf = ws;
  u16* wp_bf = ws + 110592;
  u16* qkv1  = ws + 147456;                       // 4*576*65536 bf16 (NCHW)
  u16* qkvb  = qkv1 + (size_t)150994944;          // 4*576*65536 bf16 (NCHW)
  u16* attnb = qkv1;

  hipLaunchKernelGGL(k_wcvt, dim3(432), dim3(256), 0, stream, wq, wpr, wq_bf, wp_bf);
  hipLaunchKernelGGL(k_qkv,  dim3(256, 4), dim3(768), 0, stream, x, wq_bf, qkv1);
  hipLaunchKernelGGL(k_dw,   dim3(32, 576, 4), dim3(256), 0, stream, qkv1, wdw, qkvb);
  hipLaunchKernelGGL(k_msa,  dim3(512, 4), dim3(256), 0, stream, qkvb, attnb);
  hipLaunchKernelGGL(k_proj, dim3(256, 4), dim3(512), 0, stream, attnb, wp_bf, out);
}